// Round 7
// baseline (341.678 us; speedup 1.0000x reference)
//
#include <hip/hip_runtime.h>
#include <math.h>

#define AN 4096
#define CN 8
#define FN 64
#define ACN (AN*CN)   // 32768

typedef __attribute__((ext_vector_type(8))) short bf16x8;
typedef __attribute__((ext_vector_type(4))) float f32x4;

// Direct global->LDS DMA, 16B per lane: lane l writes lds_dest + l*16.
#define GLL16(gsrc, ldst) \
    __builtin_amdgcn_global_load_lds( \
        (const __attribute__((address_space(1))) void*)(gsrc), \
        (__attribute__((address_space(3))) void*)(ldst), 16, 0, 0)

__device__ inline unsigned short f2bf(float f) {
    unsigned u = __float_as_uint(f);
    unsigned r = ((u >> 16) & 1) + 0x7FFFu;   // round-to-nearest-even
    return (unsigned short)((u + r) >> 16);
}

// ===========================================================================
// DIAGNOSTIC A/B ROUND:
//   k2_argmax  (round-6 body, VERIFIED)  replicated x6 -> writes pP (authoritative)
//   k2_hiocc   (new: B-from-global, 3 waves/SIMD) replicated x6 -> writes DEAD pP4
// Readout: top-5 shows the slower variant's counters; dur arithmetic
// (dur ~ 71 + 6X + 6Y) recovers the other. Result correctness depends only on
// the verified k2_argmax.
// ===========================================================================

// ---------------------------------------------------------------------------
// K1: normalize -> xnb bf16 [c][a][f] + inv[a*8+c].
// ---------------------------------------------------------------------------
__global__ __launch_bounds__(256) void k1_normalize(const float* __restrict__ x,
                                                    unsigned short* __restrict__ xnb,
                                                    float* __restrict__ inv)
{
    int tid  = threadIdx.x;
    int grp  = tid >> 4;
    int slot = tid & 15;
    #pragma unroll
    for (int s = 0; s < 4; ++s) {
        int V = blockIdx.x * 64 + s * 16 + grp;      // 0..32767 = a*8+c
        const float4 v = *(const float4*)(x + (size_t)V * FN + slot * 4);
        float ss = v.x*v.x + v.y*v.y + v.z*v.z + v.w*v.w;
        ss += __shfl_xor(ss, 1);
        ss += __shfl_xor(ss, 2);
        ss += __shfl_xor(ss, 4);
        ss += __shfl_xor(ss, 8);
        float sc = 1.0f / fmaxf(sqrtf(ss), 1e-6f);
        int a = V >> 3, c = V & 7;
        ushort4 ob;
        ob.x = f2bf(v.x * sc); ob.y = f2bf(v.y * sc);
        ob.z = f2bf(v.z * sc); ob.w = f2bf(v.w * sc);
        *(ushort4*)(xnb + ((size_t)c * AN + a) * FN + slot * 4) = ob;
        if (slot == 0) inv[V] = sc;
    }
}

// ---------------------------------------------------------------------------
// K2 variant A: round-6 body (full unroll, gload_lds staging, barrier-free),
// replicated x6 via blockIdx mask. Verified correct in round 6.
// ---------------------------------------------------------------------------
__global__ __launch_bounds__(256, 2) void k2_argmax(const unsigned short* __restrict__ xnb,
                                                    unsigned int* __restrict__ pP)
{
    __shared__ char ldsc[5 * 16384];   // A | B0 | B1 | B2 | B3

    int blk  = blockIdx.x & 511;       // x6 replicas
    int half = blk & 1;
    int rt   = (blk >> 1) & 31;
    int c    = blk >> 6;
    int a0   = rt * 128;
    int b0base = half * 2048;

    const char* __restrict__ Xc = (const char*)(xnb + (size_t)c * AN * FN);

    int tid  = threadIdx.x;
    int lane = tid & 63;
    int w    = tid >> 6;
    int l15  = lane & 15;
    int quad = lane >> 4;
    int srow = lane >> 3;
    int sslot = lane & 7;

    int gl_lane = srow * 128 + ((sslot ^ srow) << 4);
    const char* gA = Xc + (size_t)(a0 + w * 32) * 128 + gl_lane;
    const char* gB = Xc + (size_t)(b0base + w * 32) * 128 + gl_lane;
    char* ldsA = ldsc + w * 4096;
    char* ldsB = ldsc + 16384 + w * 4096;

    GLL16(gA,        ldsA);
    GLL16(gA + 1024, ldsA + 1024);
    GLL16(gA + 2048, ldsA + 2048);
    GLL16(gA + 3072, ldsA + 3072);
    __syncthreads();

    int ab0 = l15 * 128 + ((quad ^ (l15 & 7)) << 4);
    int ab1 = ab0 ^ 64;
    bf16x8 afr[8][2];
    #pragma unroll
    for (int mi = 0; mi < 8; ++mi) {
        afr[mi][0] = *(const bf16x8*)(ldsc + ab0 + mi * 2048);
        afr[mi][1] = *(const bf16x8*)(ldsc + ab1 + mi * 2048);
    }

    int rb0 = 16384 + (w * 32 + l15) * 128 + ((quad ^ (l15 & 7)) << 4);
    int rb1 = rb0 ^ 64;

    float bestp[32];
    #pragma unroll
    for (int i = 0; i < 32; ++i) bestp[i] = 0.0f;

    const f32x4 two = {2.0f, 2.0f, 2.0f, 2.0f};

#define STAGE_B(IT) do { \
        const char* _g = gB + (size_t)(IT) * 16384; \
        char* _l = ldsB + ((IT) & 3) * 16384; \
        GLL16(_g,        _l); \
        GLL16(_g + 1024, _l + 1024); \
        GLL16(_g + 2048, _l + 2048); \
        GLL16(_g + 3072, _l + 3072); \
    } while (0)

    STAGE_B(0);
    STAGE_B(1);
    STAGE_B(2);

    #pragma unroll
    for (int it = 0; it < 16; ++it) {
        if (it <= 12) STAGE_B(it + 3);

        if (it <= 12)      { asm volatile("s_waitcnt vmcnt(12)" ::: "memory"); }
        else if (it == 13) { asm volatile("s_waitcnt vmcnt(8)"  ::: "memory"); }
        else if (it == 14) { asm volatile("s_waitcnt vmcnt(4)"  ::: "memory"); }
        else               { asm volatile("s_waitcnt vmcnt(0)"  ::: "memory"); }

        const int bo = (it & 3) * 16384;

        f32x4 acc[8][2];
        #pragma unroll
        for (int ks = 0; ks < 2; ++ks) {
            #pragma unroll
            for (int ni = 0; ni < 2; ++ni) {
                bf16x8 bfr = *(const bf16x8*)(ldsc + (ks ? rb1 : rb0) + bo + ni * 2048);
                #pragma unroll
                for (int mi = 0; mi < 8; ++mi)
                    acc[mi][ni] = __builtin_amdgcn_mfma_f32_16x16x32_bf16(
                        afr[mi][ks], bfr, (ks == 0) ? two : acc[mi][ni], 0, 0, 0);
            }
        }

        int colblk = b0base + it * 128 + w * 32;
        #pragma unroll
        for (int mi = 0; mi < 8; ++mi) {
            int rfrag = a0 + mi * 16;
            #pragma unroll
            for (int r = 0; r < 4; ++r) {
                unsigned p0 = (__float_as_uint(acc[mi][0][r]) & 0xFFFFF000u)
                            | (unsigned)(colblk + l15);
                unsigned p1 = (__float_as_uint(acc[mi][1][r]) & 0xFFFFF000u)
                            | (unsigned)(colblk + 16 + l15);
                float c0 = __uint_as_float(p0);
                float c1 = __uint_as_float(p1);
                if (rfrag == colblk)      { if (l15 == quad * 4 + r) c0 = 0.0f; }
                if (rfrag == colblk + 16) { if (l15 == quad * 4 + r) c1 = 0.0f; }
                int bi = mi * 4 + r;
                bestp[bi] = fmaxf(fmaxf(c0, c1), bestp[bi]);
            }
        }
    }
#undef STAGE_B

    #pragma unroll
    for (int i = 0; i < 32; ++i) {
        float v = bestp[i];
        v = fmaxf(v, __shfl_xor(v, 1));
        v = fmaxf(v, __shfl_xor(v, 2));
        v = fmaxf(v, __shfl_xor(v, 4));
        v = fmaxf(v, __shfl_xor(v, 8));
        bestp[i] = v;
    }
    __syncthreads();
    float* red = (float*)ldsc;
    if (l15 == 0) {
        #pragma unroll
        for (int mi = 0; mi < 8; ++mi)
            #pragma unroll
            for (int r = 0; r < 4; ++r)
                red[w * 128 + mi * 16 + quad * 4 + r] = bestp[mi * 4 + r];
    }
    __syncthreads();
    if (tid < 128) {
        float p = fmaxf(fmaxf(red[tid], red[128 + tid]),
                        fmaxf(red[256 + tid], red[384 + tid]));
        int a = a0 + tid;
        pP[(size_t)half * ACN + (size_t)a * CN + c] = __float_as_uint(p);
    }
}

// ---------------------------------------------------------------------------
// K2 variant B (PROBE): B-fragments read directly from global (L2-resident
// panel), LDS holds only A (16 KB) -> ~160 VGPR, 3 waves/SIMD, no staging
// machinery. Grid 1024 logical = 8c x 32rt x 4 col-quarters; per block 16
// iters of 64 cols; wave w owns 16 cols. Writes pP4 (DEAD this round).
// ---------------------------------------------------------------------------
__global__ __launch_bounds__(256) void k2_hiocc(const unsigned short* __restrict__ xnb,
                                                unsigned int* __restrict__ pP4)
{
    __shared__ char ldsc[16384];       // A tile only

    int blk  = blockIdx.x & 1023;      // x6 replicas
    int q    = blk & 3;
    int rt   = (blk >> 2) & 31;
    int c    = blk >> 7;
    int a0   = rt * 128;
    int col0 = q * 1024;

    const char* __restrict__ Xc = (const char*)(xnb + (size_t)c * AN * FN);

    int tid  = threadIdx.x;
    int lane = tid & 63;
    int w    = tid >> 6;
    int l15  = lane & 15;
    int quad = lane >> 4;
    int srow = lane >> 3;
    int sslot = lane & 7;

    // ---- stage A tile (swizzled, as in variant A) ----
    int gl_lane = srow * 128 + ((sslot ^ srow) << 4);
    const char* gA = Xc + (size_t)(a0 + w * 32) * 128 + gl_lane;
    char* ldsA = ldsc + w * 4096;
    GLL16(gA,        ldsA);
    GLL16(gA + 1024, ldsA + 1024);
    GLL16(gA + 2048, ldsA + 2048);
    GLL16(gA + 3072, ldsA + 3072);
    __syncthreads();

    int ab0 = l15 * 128 + ((quad ^ (l15 & 7)) << 4);
    int ab1 = ab0 ^ 64;
    bf16x8 afr[8][2];
    #pragma unroll
    for (int mi = 0; mi < 8; ++mi) {
        afr[mi][0] = *(const bf16x8*)(ldsc + ab0 + mi * 2048);
        afr[mi][1] = *(const bf16x8*)(ldsc + ab1 + mi * 2048);
    }

    // ---- per-lane global B base: row = col0 + w*16 + l15, chunk quad ----
    const char* gB = Xc + (size_t)(col0 + w * 16 + l15) * 128 + quad * 16;

    float bestp[32];
    #pragma unroll
    for (int i = 0; i < 32; ++i) bestp[i] = 0.0f;

    const f32x4 two = {2.0f, 2.0f, 2.0f, 2.0f};

    // depth-1 prefetch of the two 16B B-fragments (ks=0,1)
    bf16x8 b0 = *(const bf16x8*)(gB);
    bf16x8 b1 = *(const bf16x8*)(gB + 64);

    #pragma unroll 2
    for (int it = 0; it < 16; ++it) {
        int itn = (it < 15) ? it + 1 : 15;     // clamped (last prefetch unused)
        bf16x8 n0 = *(const bf16x8*)(gB + (size_t)itn * 8192);
        bf16x8 n1 = *(const bf16x8*)(gB + (size_t)itn * 8192 + 64);

        f32x4 acc[8];
        #pragma unroll
        for (int mi = 0; mi < 8; ++mi)
            acc[mi] = __builtin_amdgcn_mfma_f32_16x16x32_bf16(afr[mi][0], b0, two, 0, 0, 0);
        #pragma unroll
        for (int mi = 0; mi < 8; ++mi)
            acc[mi] = __builtin_amdgcn_mfma_f32_16x16x32_bf16(afr[mi][1], b1, acc[mi], 0, 0, 0);

        int cfrag = col0 + it * 64 + w * 16;
        #pragma unroll
        for (int mi = 0; mi < 8; ++mi) {
            int rfrag = a0 + mi * 16;
            #pragma unroll
            for (int r = 0; r < 4; ++r) {
                unsigned pb = (__float_as_uint(acc[mi][r]) & 0xFFFFF000u)
                            | (unsigned)(cfrag + l15);
                float c0 = __uint_as_float(pb);
                if (rfrag == cfrag) { if (l15 == quad * 4 + r) c0 = 0.0f; }
                int bi = mi * 4 + r;
                bestp[bi] = fmaxf(c0, bestp[bi]);
            }
        }

        b0 = n0; b1 = n1;
    }

    #pragma unroll
    for (int i = 0; i < 32; ++i) {
        float v = bestp[i];
        v = fmaxf(v, __shfl_xor(v, 1));
        v = fmaxf(v, __shfl_xor(v, 2));
        v = fmaxf(v, __shfl_xor(v, 4));
        v = fmaxf(v, __shfl_xor(v, 8));
        bestp[i] = v;
    }
    __syncthreads();
    float* red = (float*)ldsc;
    if (l15 == 0) {
        #pragma unroll
        for (int mi = 0; mi < 8; ++mi)
            #pragma unroll
            for (int r = 0; r < 4; ++r)
                red[w * 128 + mi * 16 + quad * 4 + r] = bestp[mi * 4 + r];
    }
    __syncthreads();
    if (tid < 128) {
        float p = fmaxf(fmaxf(red[tid], red[128 + tid]),
                        fmaxf(red[256 + tid], red[384 + tid]));
        int a = a0 + tid;
        pP4[(size_t)q * ACN + (size_t)a * CN + c] = __float_as_uint(p);
    }
}

// ---------------------------------------------------------------------------
// K3: merge halves (from verified pP), exact fp32 distance + log, reduce.
// ---------------------------------------------------------------------------
__global__ __launch_bounds__(256) void k3_dist(const float* __restrict__ x,
                                               const float* __restrict__ inv,
                                               const unsigned int* __restrict__ pP,
                                               float* __restrict__ partials)
{
    int tid = threadIdx.x;
    int id = blockIdx.x * 256 + tid;            // a*8 + c
    float p0 = __uint_as_float(pP[id]);
    float p1 = __uint_as_float(pP[ACN + id]);
    unsigned pm = __float_as_uint(fmaxf(p0, p1));
    int m = (int)(pm & 0xFFFu);
    int c = id & 7;
    int idb = m * CN + c;
    float sa = inv[id];
    float sb = inv[idb];
    const float* xa = x + (size_t)id  * FN;
    const float* xb = x + (size_t)idb * FN;
    float ss = 0.0f;
    #pragma unroll
    for (int q = 0; q < 16; ++q) {
        float4 va = *(const float4*)(xa + 4 * q);
        float4 vb = *(const float4*)(xb + 4 * q);
        float d0 = va.x * sa - vb.x * sb + 1e-6f;
        float d1 = va.y * sa - vb.y * sb + 1e-6f;
        float d2 = va.z * sa - vb.z * sb + 1e-6f;
        float d3 = va.w * sa - vb.w * sb + 1e-6f;
        ss += d0*d0 + d1*d1 + d2*d2 + d3*d3;
    }
    float val = logf(sqrtf(ss) + 1e-6f);

    float t = val;
    #pragma unroll
    for (int off = 32; off > 0; off >>= 1) t += __shfl_down(t, off);
    __shared__ float ws4[4];
    if ((tid & 63) == 0) ws4[tid >> 6] = t;
    __syncthreads();
    if (tid == 0)
        partials[blockIdx.x] = ws4[0] + ws4[1] + ws4[2] + ws4[3];
}

// ---------------------------------------------------------------------------
// K4: out = -sum(partials)/32768
// ---------------------------------------------------------------------------
__global__ __launch_bounds__(64) void k4_final(const float* __restrict__ partials,
                                               float* __restrict__ out)
{
    int t = threadIdx.x;
    float v = partials[t] + partials[t + 64];
    #pragma unroll
    for (int off = 32; off > 0; off >>= 1) v += __shfl_down(v, off);
    if (t == 0) out[0] = -v / (float)ACN;
}

extern "C" void kernel_launch(void* const* d_in, const int* in_sizes, int n_in,
                              void* d_out, int out_size, void* d_ws, size_t ws_size,
                              hipStream_t stream)
{
    const float* x = (const float*)d_in[0];
    unsigned short* xnb = (unsigned short*)d_ws;               // 4 MB bf16 [c][a][f]
    float* inv = (float*)(xnb + (size_t)AN * CN * FN);         // 128 KB inverse norms
    unsigned int* pP = (unsigned int*)(inv + ACN);             // 256 KB packed argmax
    float* partials = (float*)(pP + 2 * ACN);                  // 512 B
    unsigned int* pP4 = (unsigned int*)(partials + 128);       // 512 KB (probe, dead)

    k1_normalize<<<512, 256, 0, stream>>>(x, xnb, inv);
    k2_argmax  <<<512 * 6, 256, 0, stream>>>(xnb, pP);         // variant A x6 (authoritative)
    k2_hiocc   <<<1024 * 6, 256, 0, stream>>>(xnb, pP4);       // variant B x6 (dead probe)
    k3_dist    <<<128, 256, 0, stream>>>(x, inv, pP, partials);
    k4_final   <<<1, 64, 0, stream>>>(partials, (float*)d_out);
}

// Round 9
// 95.517 us; speedup vs baseline: 3.5772x; 3.5772x over previous
//
#include <hip/hip_runtime.h>
#include <math.h>

#define AN 4096
#define CN 8
#define FN 64
#define ACN (AN*CN)   // 32768
#define NSEG 4        // column segments; k2 grid = 8*32*NSEG = 1024
#define ITERS 8       // col-iters per block = 4096/NSEG/128

typedef __attribute__((ext_vector_type(8))) short bf16x8;
typedef __attribute__((ext_vector_type(4))) float f32x4;

// Direct global->LDS DMA, 16B per lane: lane l writes lds_dest + l*16.
#define GLL16(gsrc, ldst) \
    __builtin_amdgcn_global_load_lds( \
        (const __attribute__((address_space(1))) void*)(gsrc), \
        (__attribute__((address_space(3))) void*)(ldst), 16, 0, 0)

__device__ inline unsigned short f2bf(float f) {
    unsigned u = __float_as_uint(f);
    unsigned r = ((u >> 16) & 1) + 0x7FFFu;   // round-to-nearest-even
    return (unsigned short)((u + r) >> 16);
}

// ---------------------------------------------------------------------------
// K1: normalize -> xnb bf16 [c][a][f] + inv[a*8+c] fp32 inverse norms.
// k3 recomputes x*inv (identical multiply, bit-exact).
// ---------------------------------------------------------------------------
__global__ __launch_bounds__(256) void k1_normalize(const float* __restrict__ x,
                                                    unsigned short* __restrict__ xnb,
                                                    float* __restrict__ inv)
{
    int tid  = threadIdx.x;
    int grp  = tid >> 4;
    int slot = tid & 15;
    #pragma unroll
    for (int s = 0; s < 4; ++s) {
        int V = blockIdx.x * 64 + s * 16 + grp;      // 0..32767 = a*8+c
        const float4 v = *(const float4*)(x + (size_t)V * FN + slot * 4);
        float ss = v.x*v.x + v.y*v.y + v.z*v.z + v.w*v.w;
        ss += __shfl_xor(ss, 1);
        ss += __shfl_xor(ss, 2);
        ss += __shfl_xor(ss, 4);
        ss += __shfl_xor(ss, 8);
        float sc = 1.0f / fmaxf(sqrtf(ss), 1e-6f);
        int a = V >> 3, c = V & 7;
        ushort4 ob;
        ob.x = f2bf(v.x * sc); ob.y = f2bf(v.y * sc);
        ob.z = f2bf(v.z * sc); ob.w = f2bf(v.w * sc);
        *(ushort4*)(xnb + ((size_t)c * AN + a) * FN + slot * 4) = ob;
        if (slot == 0) inv[V] = sc;
    }
}

// ---------------------------------------------------------------------------
// K2: round-6 verified body, NSEG=4 column segments -> grid 1024 (NOT 2048:
// r8's failure was launching 512*NSEG; the decomposition seg(2b)|rt(5b)|c(3b)
// covers exactly 8*32*4=1024 blocks. Grid==product-of-dims now asserted by
// construction in kernel_launch).
// REGIME FIX (r7 diagnosis): at grid 512 / 2 blocks/CU all blocks are
// co-resident in one batch -> kernel time = single-block LATENCY (~22us);
// x6-replication measured steady-state THROUGHPUT ~13us. Grid 1024 queues
// 2 batches/CU with halved per-block latency -> block-level overlap.
// Body: full unroll, gload_lds staging with pre-swizzled source, wave-private
// B slabs, barrier-free counted vmcnt, packed argmax (exact fmax; diagonal
// excluded on its fragment). LDS 80KB (A | B0..B3) -> 2 blocks/CU.
// ---------------------------------------------------------------------------
__global__ __launch_bounds__(256, 2) void k2_argmax(const unsigned short* __restrict__ xnb,
                                                    unsigned int* __restrict__ pP)
{
    __shared__ char ldsc[5 * 16384];   // A | B0 | B1 | B2 | B3

    int blk  = blockIdx.x;             // 0..1023
    int seg  = blk & (NSEG - 1);
    int rt   = (blk >> 2) & 31;
    int c    = blk >> 7;               // 0..7
    int a0   = rt * 128;
    int col0 = seg * 1024;

    const char* __restrict__ Xc = (const char*)(xnb + (size_t)c * AN * FN); // row r at byte r*128

    int tid  = threadIdx.x;
    int lane = tid & 63;
    int w    = tid >> 6;      // wave 0..3
    int l15  = lane & 15;
    int quad = lane >> 4;
    int srow = lane >> 3;
    int sslot = lane & 7;

    // per-lane global staging offset within a 32-row slab (chunk pre-swizzled)
    int gl_lane = srow * 128 + ((sslot ^ srow) << 4);
    const char* gA = Xc + (size_t)(a0 + w * 32) * 128 + gl_lane;
    const char* gB = Xc + (size_t)(col0 + w * 32) * 128 + gl_lane;
    char* ldsA = ldsc + w * 4096;
    char* ldsB = ldsc + 16384 + w * 4096;

    // ---- stage A tile (4 DMA / wave) ----
    GLL16(gA,        ldsA);
    GLL16(gA + 1024, ldsA + 1024);
    GLL16(gA + 2048, ldsA + 2048);
    GLL16(gA + 3072, ldsA + 3072);
    __syncthreads();          // drains vmcnt; A visible to all waves

    // ---- A fragments: 2 base addrs + immediates ----
    int ab0 = l15 * 128 + ((quad ^ (l15 & 7)) << 4);
    int ab1 = ab0 ^ 64;
    bf16x8 afr[8][2];
    #pragma unroll
    for (int mi = 0; mi < 8; ++mi) {
        afr[mi][0] = *(const bf16x8*)(ldsc + ab0 + mi * 2048);
        afr[mi][1] = *(const bf16x8*)(ldsc + ab1 + mi * 2048);
    }

    int rb0 = 16384 + (w * 32 + l15) * 128 + ((quad ^ (l15 & 7)) << 4);
    int rb1 = rb0 ^ 64;

    float bestp[32];
    #pragma unroll
    for (int i = 0; i < 32; ++i) bestp[i] = 0.0f;

    const f32x4 two = {2.0f, 2.0f, 2.0f, 2.0f};

#define STAGE_B(IT) do { \
        const char* _g = gB + (size_t)(IT) * 16384; \
        char* _l = ldsB + ((IT) & 3) * 16384; \
        GLL16(_g,        _l); \
        GLL16(_g + 1024, _l + 1024); \
        GLL16(_g + 2048, _l + 2048); \
        GLL16(_g + 3072, _l + 3072); \
    } while (0)

    STAGE_B(0);
    STAGE_B(1);
    STAGE_B(2);

    #pragma unroll
    for (int it = 0; it < ITERS; ++it) {
        if (it <= ITERS - 4) STAGE_B(it + 3);

        if (it <= ITERS - 4)      { asm volatile("s_waitcnt vmcnt(12)" ::: "memory"); }
        else if (it == ITERS - 3) { asm volatile("s_waitcnt vmcnt(8)"  ::: "memory"); }
        else if (it == ITERS - 2) { asm volatile("s_waitcnt vmcnt(4)"  ::: "memory"); }
        else                      { asm volatile("s_waitcnt vmcnt(0)"  ::: "memory"); }

        const int bo = (it & 3) * 16384;        // compile-time (full unroll)

        f32x4 acc[8][2];
        #pragma unroll
        for (int ks = 0; ks < 2; ++ks) {
            #pragma unroll
            for (int ni = 0; ni < 2; ++ni) {
                bf16x8 bfr = *(const bf16x8*)(ldsc + (ks ? rb1 : rb0) + bo + ni * 2048);
                #pragma unroll
                for (int mi = 0; mi < 8; ++mi)
                    acc[mi][ni] = __builtin_amdgcn_mfma_f32_16x16x32_bf16(
                        afr[mi][ks], bfr, (ks == 0) ? two : acc[mi][ni], 0, 0, 0);
            }
        }

        // ---- packed argmax update ----
        int colblk = col0 + it * 128 + w * 32;
        #pragma unroll
        for (int mi = 0; mi < 8; ++mi) {
            int rfrag = a0 + mi * 16;
            #pragma unroll
            for (int r = 0; r < 4; ++r) {
                unsigned p0 = (__float_as_uint(acc[mi][0][r]) & 0xFFFFF000u)
                            | (unsigned)(colblk + l15);
                unsigned p1 = (__float_as_uint(acc[mi][1][r]) & 0xFFFFF000u)
                            | (unsigned)(colblk + 16 + l15);
                float c0 = __uint_as_float(p0);
                float c1 = __uint_as_float(p1);
                if (rfrag == colblk)      { if (l15 == quad * 4 + r) c0 = 0.0f; }
                if (rfrag == colblk + 16) { if (l15 == quad * 4 + r) c1 = 0.0f; }
                int bi = mi * 4 + r;
                bestp[bi] = fmaxf(fmaxf(c0, c1), bestp[bi]);
            }
        }
    }
#undef STAGE_B

    // ---- reduce across the 16 column-lanes ----
    #pragma unroll
    for (int i = 0; i < 32; ++i) {
        float v = bestp[i];
        v = fmaxf(v, __shfl_xor(v, 1));
        v = fmaxf(v, __shfl_xor(v, 2));
        v = fmaxf(v, __shfl_xor(v, 4));
        v = fmaxf(v, __shfl_xor(v, 8));
        bestp[i] = v;
    }
    __syncthreads();                    // all waves done; A region reusable
    float* red = (float*)ldsc;          // red[w][128]
    if (l15 == 0) {
        #pragma unroll
        for (int mi = 0; mi < 8; ++mi)
            #pragma unroll
            for (int r = 0; r < 4; ++r)
                red[w * 128 + mi * 16 + quad * 4 + r] = bestp[mi * 4 + r];
    }
    __syncthreads();
    if (tid < 128) {
        float p = fmaxf(fmaxf(red[tid], red[128 + tid]),
                        fmaxf(red[256 + tid], red[384 + tid]));
        int a = a0 + tid;
        pP[(size_t)seg * ACN + (size_t)a * CN + c] = __float_as_uint(p);
    }
}

// ---------------------------------------------------------------------------
// K3: merge NSEG segments, unpack index, exact fp32 distance + log, reduce.
// ---------------------------------------------------------------------------
__global__ __launch_bounds__(256) void k3_dist(const float* __restrict__ x,
                                               const float* __restrict__ inv,
                                               const unsigned int* __restrict__ pP,
                                               float* __restrict__ partials)
{
    int tid = threadIdx.x;
    int id = blockIdx.x * 256 + tid;            // a*8 + c
    float p0 = __uint_as_float(pP[id]);
    float p1 = __uint_as_float(pP[ACN + id]);
    float p2 = __uint_as_float(pP[2 * ACN + id]);
    float p3 = __uint_as_float(pP[3 * ACN + id]);
    unsigned pm = __float_as_uint(fmaxf(fmaxf(p0, p1), fmaxf(p2, p3)));
    int m = (int)(pm & 0xFFFu);
    int c = id & 7;
    int idb = m * CN + c;
    float sa = inv[id];
    float sb = inv[idb];
    const float* xa = x + (size_t)id  * FN;
    const float* xb = x + (size_t)idb * FN;
    float ss = 0.0f;
    #pragma unroll
    for (int q = 0; q < 16; ++q) {
        float4 va = *(const float4*)(xa + 4 * q);
        float4 vb = *(const float4*)(xb + 4 * q);
        float d0 = va.x * sa - vb.x * sb + 1e-6f;
        float d1 = va.y * sa - vb.y * sb + 1e-6f;
        float d2 = va.z * sa - vb.z * sb + 1e-6f;
        float d3 = va.w * sa - vb.w * sb + 1e-6f;
        ss += d0*d0 + d1*d1 + d2*d2 + d3*d3;
    }
    float val = logf(sqrtf(ss) + 1e-6f);

    float t = val;
    #pragma unroll
    for (int off = 32; off > 0; off >>= 1) t += __shfl_down(t, off);
    __shared__ float ws4[4];
    if ((tid & 63) == 0) ws4[tid >> 6] = t;
    __syncthreads();
    if (tid == 0)
        partials[blockIdx.x] = ws4[0] + ws4[1] + ws4[2] + ws4[3];
}

// ---------------------------------------------------------------------------
// K4: out = -sum(partials)/32768
// ---------------------------------------------------------------------------
__global__ __launch_bounds__(64) void k4_final(const float* __restrict__ partials,
                                               float* __restrict__ out)
{
    int t = threadIdx.x;
    float v = partials[t] + partials[t + 64];
    #pragma unroll
    for (int off = 32; off > 0; off >>= 1) v += __shfl_down(v, off);
    if (t == 0) out[0] = -v / (float)ACN;
}

extern "C" void kernel_launch(void* const* d_in, const int* in_sizes, int n_in,
                              void* d_out, int out_size, void* d_ws, size_t ws_size,
                              hipStream_t stream)
{
    const float* x = (const float*)d_in[0];
    unsigned short* xnb = (unsigned short*)d_ws;               // 4 MB bf16 [c][a][f]
    float* inv = (float*)(xnb + (size_t)AN * CN * FN);         // 128 KB inverse norms
    unsigned int* pP = (unsigned int*)(inv + ACN);             // 512 KB packed argmax (4 segs)
    float* partials = (float*)(pP + NSEG * ACN);               // 512 B

    k1_normalize<<<512, 256, 0, stream>>>(x, xnb, inv);
    k2_argmax  <<<CN * 32 * NSEG, 256, 0, stream>>>(xnb, pP);  // 8*32*4 = 1024 == product of dims
    k3_dist    <<<128, 256, 0, stream>>>(x, inv, pP, partials);
    k4_final   <<<1, 64, 0, stream>>>(partials, (float*)d_out);
}